// Round 1
// baseline (1370.849 us; speedup 1.0000x reference)
//
#include <hip/hip_runtime.h>

#define DEG 17
#define NSTEPS 32
#define HD 96
#define BB 16
#define NN 64
#define NODES (BB*NN)   // 1024
#define NBLK 512        // 2 nodes per block -> 2 blocks/CU (12 waves/CU)

// ws float offsets (totals unchanged vs baseline; lossP/cntP overlay dead xin)
#define WS_H      0
#define WS_S      98304
#define WS_U0     196608
#define WS_U1     393216
#define WS_XIN    590352
#define WS_GX     688656
#define WS_W1P    1081872
#define WS_W2P    1094160
#define WS_LOSSP  WS_XIN                // xin dead after gx_kernel
#define WS_CNTP   (WS_XIN + 16384)      // ints

// ---------------- init0: pad W1/W2 to [96][128]: 32 groups of 4 (3 valid + 1 zero)
__global__ void wpad_kernel(const float* __restrict__ msg_Ws,
                            float* __restrict__ W1p, float* __restrict__ W2p)
{
  const int k = blockIdx.x;        // 0..95
  const int tid = threadIdx.x;     // 0..127
  const int jg = tid >> 2, jj = tid & 3;
  float v1 = 0.f, v2 = 0.f;
  if (jj < 3) {
    v1 = msg_Ws[k*96 + jg*3 + jj];
    v2 = msg_Ws[9216 + k*96 + jg*3 + jj];
  }
  W1p[k*128 + tid] = v1;
  W2p[k*128 + tid] = v2;
}

// ---------------- init1: embedding + input MLP -> xin; also u0 self-half = msg0_b
__global__ void init_kernel(
    const int* __restrict__ x,
    const float* __restrict__ digit_emb,
    const float* __restrict__ row_emb,
    const float* __restrict__ col_emb,
    const float* __restrict__ in0_W,
    const float* __restrict__ in0_b,
    const float* __restrict__ in_Ws,
    const float* __restrict__ in_bs,
    const float* __restrict__ msg0_b,
    float* __restrict__ xin,
    float* __restrict__ u0)
{
  const int node = blockIdx.x;
  const int j = threadIdx.x;
  const int n = node & 63;
  const int r = n >> 3, c = n & 7;
  __shared__ float feat[48];
  __shared__ float za[HD];
  __shared__ float zb[HD];
  if (j < 16)      feat[j] = digit_emb[x[node]*16 + j];
  else if (j < 32) feat[j] = row_emb[r*16 + (j-16)];
  else if (j < 48) feat[j] = col_emb[c*16 + (j-32)];
  // fold msg0_b into u self-part for step 0 (steps add it in the u epilogue)
  u0[node*192 + 96 + j] = msg0_b[j];
  __syncthreads();
  float a = in0_b[j];
  for (int k = 0; k < 48; ++k) a = fmaf(feat[k], in0_W[k*HD + j], a);
  za[j] = fmaxf(a, 0.f);
  __syncthreads();
  a = in_bs[j];
  for (int k = 0; k < HD; ++k) a = fmaf(za[k], in_Ws[k*HD + j], a);
  zb[j] = fmaxf(a, 0.f);
  __syncthreads();
  a = in_bs[HD + j];
  for (int k = 0; k < HD; ++k) a = fmaf(zb[k], in_Ws[9216 + k*HD + j], a);
  za[j] = fmaxf(a, 0.f);
  __syncthreads();
  a = in_bs[2*HD + j];
  for (int k = 0; k < HD; ++k) a = fmaf(za[k], in_Ws[2*9216 + k*HD + j], a);
  xin[node*HD + j] = a;
}

// ---------------- init2: gx = xin @ W_ih[96:192] + b_ih + b_hh (one-time)
__global__ __launch_bounds__(384) void gx_kernel(
    const float* __restrict__ xin, const float* __restrict__ W_ih,
    const float* __restrict__ b_ih, const float* __restrict__ b_hh,
    float* __restrict__ gx)
{
  __shared__ float xs[4*HD];
  const int tid = threadIdx.x;
  const int base = blockIdx.x * 4;
  {
    const int m = tid / HD, k = tid - m*HD;
    xs[m*HD + k] = xin[(base+m)*HD + k];
  }
  __syncthreads();
  const int j = tid;  // 0..383
  float a0 = b_ih[j] + b_hh[j], a1 = a0, a2 = a0, a3 = a0;
  for (int k = 0; k < HD; ++k) {
    const float w = W_ih[(96+k)*384 + j];
    a0 = fmaf(xs[k], w, a0);
    a1 = fmaf(xs[HD+k], w, a1);
    a2 = fmaf(xs[2*HD+k], w, a2);
    a3 = fmaf(xs[3*HD+k], w, a3);
  }
  gx[(base+0)*384 + j] = a0;
  gx[(base+1)*384 + j] = a1;
  gx[(base+2)*384 + j] = a2;
  gx[(base+3)*384 + j] = a3;
}

// ---------------- one recurrent step: 2 nodes/block, 512 blocks ----------------
__global__ __launch_bounds__(384, 3) void step_kernel(
    const float* __restrict__ u_prev, float* __restrict__ u_next,
    float* __restrict__ h, float* __restrict__ s,
    const float* __restrict__ gx,
    const int* __restrict__ edges,
    const float* __restrict__ W1p, const float* __restrict__ W2p,
    const float* __restrict__ msg0_W, const float* __restrict__ msg0_b,
    const float* __restrict__ msg_Ws, const float* __restrict__ msg_bs,
    const float* __restrict__ W_ih, const float* __restrict__ W_hh,
    const float* __restrict__ pred_W, const float* __restrict__ pred_b,
    const int* __restrict__ target,
    float* __restrict__ lossP, int* __restrict__ cntP,
    float* __restrict__ final_pred_out, int step)
{
  __shared__ float sm[15392];          // 61568 B -> 2 blocks/CU (123 KB of 160)
  float* const z1s   = sm;             // [96 k][40 rows]  (2 nodes * 20 padded rows)
  float* const z2s   = sm + 3840;      // [96 k][40 rows]
  float* const pp    = sm + 7680;      // 6144: partial buffers (P3 / PL / PU)
  float* const s3t   = sm + 13824;     // [96][2]
  float* const msgh  = sm + 14016;     // [192 k][2 m]  (msg 0..95, h 96..191)
  float* const h2t   = sm + 14400;     // [96][2]
  float* const gates = sm + 14592;     // [2][384]
  float* const lgt   = sm + 15360;     // 32

  const int tid = threadIdx.x;
  const int blk = blockIdx.x;
  const int base = blk * 2;            // first node of block
  const int bb = blk >> 5;             // batch index (32 blocks/batch)
  const int nbase = (blk & 31) * 2;    // node-in-batch of m=0

  // ===== phase 1: z1 rows via (row, k-chunk) ownership: float4 loads,
  //        <=3-way LDS write conflicts (old layout was ~32-way). =====
  if (tid < 320) {
    const int row = tid % 40;          // m*20 + r
    const int kh  = tid / 40;          // 0..7, 12 k each
    const int m = row / 20, r = row % 20;
    const int k0 = kh * 12;
    if (r < DEG) {
      const int nbr = edges[(nbase + m)*DEG + r];
      const float* uep = u_prev + (bb*64 + nbr)*192 + k0;       // edge half
      const float* usp = u_prev + (base + m)*192 + 96 + k0;     // self half (+b0 folded)
      #pragma unroll
      for (int t = 0; t < 3; ++t) {
        const float4 ue = *(const float4*)(uep + 4*t);
        const float4 us = *(const float4*)(usp + 4*t);
        z1s[(k0 + 4*t + 0)*40 + row] = fmaxf(ue.x + us.x, 0.f);
        z1s[(k0 + 4*t + 1)*40 + row] = fmaxf(ue.y + us.y, 0.f);
        z1s[(k0 + 4*t + 2)*40 + row] = fmaxf(ue.z + us.z, 0.f);
        z1s[(k0 + 4*t + 3)*40 + row] = fmaxf(ue.w + us.w, 0.f);
      }
    } else {
      #pragma unroll
      for (int t = 0; t < 12; ++t) z1s[(k0 + t)*40 + row] = 0.f;
    }
  }
  if (tid < 192) {
    s3t[tid] = 0.f;
  } else {
    const int i = tid - 192;           // stage h into k-slots 96..191
    const int m2 = i / 96, k2 = i % 96;
    msgh[(96 + k2)*2 + m2] = h[(base + m2)*HD + k2];
  }
  __syncthreads();

  // ===== phase 2: GEMM1  z2 = relu(z1 @ W1 + b1)  (40x96 @ 96x96), 320 thr =====
  if (tid < 320) {
    const int jg = tid & 31, dg = tid >> 5;    // 3 cols, 4 rows each
    const int j3 = jg*3;
    float acc[4][3];
    #pragma unroll
    for (int dd = 0; dd < 4; ++dd)
      #pragma unroll
      for (int jj = 0; jj < 3; ++jj) acc[dd][jj] = 0.f;
    #pragma unroll 4
    for (int k = 0; k < HD; ++k) {
      const float4 z = *(const float4*)&z1s[k*40 + dg*4];
      const float4 w = *(const float4*)&W1p[k*128 + jg*4];   // w.w = pad
      const float ze[4] = {z.x, z.y, z.z, z.w};
      const float we[3] = {w.x, w.y, w.z};
      #pragma unroll
      for (int dd = 0; dd < 4; ++dd)
        #pragma unroll
        for (int jj = 0; jj < 3; ++jj)
          acc[dd][jj] = fmaf(ze[dd], we[jj], acc[dd][jj]);
    }
    #pragma unroll
    for (int jj = 0; jj < 3; ++jj) {
      const float b1 = msg_bs[j3 + jj];
      float4 q;
      q.x = fmaxf(acc[0][jj] + b1, 0.f);
      q.y = fmaxf(acc[1][jj] + b1, 0.f);
      q.z = fmaxf(acc[2][jj] + b1, 0.f);
      q.w = fmaxf(acc[3][jj] + b1, 0.f);
      *(float4*)&z2s[(j3+jj)*40 + dg*4] = q;
    }
  }
  __syncthreads();

  // ===== phase 3: GEMM2 + relu + masked row-sum -> s3t[k][m], 320 thr =====
  if (tid < 320) {
    const int jg = tid & 31, dg = tid >> 5;
    const int j3 = jg*3;
    const int nd = dg / 5, dgl = dg - nd*5;
    float acc[4][3];
    #pragma unroll
    for (int dd = 0; dd < 4; ++dd)
      #pragma unroll
      for (int jj = 0; jj < 3; ++jj) acc[dd][jj] = 0.f;
    #pragma unroll 4
    for (int k = 0; k < HD; ++k) {
      const float4 z = *(const float4*)&z2s[k*40 + dg*4];
      const float4 w = *(const float4*)&W2p[k*128 + jg*4];
      const float ze[4] = {z.x, z.y, z.z, z.w};
      const float we[3] = {w.x, w.y, w.z};
      #pragma unroll
      for (int dd = 0; dd < 4; ++dd)
        #pragma unroll
        for (int jj = 0; jj < 3; ++jj)
          acc[dd][jj] = fmaf(ze[dd], we[jj], acc[dd][jj]);
    }
    const int nvalid = (dgl < 4) ? 4 : 1;      // rows 0..16 valid of 20
    #pragma unroll
    for (int jj = 0; jj < 3; ++jj) {
      const float b2 = msg_bs[96 + j3 + jj];
      float p = 0.f;
      #pragma unroll
      for (int dd = 0; dd < 4; ++dd)
        if (dd < nvalid) p += fmaxf(acc[dd][jj] + b2, 0.f);
      atomicAdd(&s3t[(j3+jj)*2 + nd], p);
    }
  }
  __syncthreads();

  // ===== phase 4: GEMM3  msg = s3 @ W3 (+17*b3 in reduce), 384 thr =====
  {
    const int jg = tid % 24, kq = tid / 24;    // kq 0..15, 6 k each
    const int j4 = jg*4, k0 = kq*6;
    const float* W3 = msg_Ws + 2*9216;
    float acc[2][4];
    #pragma unroll
    for (int m = 0; m < 2; ++m)
      #pragma unroll
      for (int jj = 0; jj < 4; ++jj) acc[m][jj] = 0.f;
    #pragma unroll
    for (int kk = 0; kk < 6; ++kk) {
      const int k = k0 + kk;
      const float2 sv = *(const float2*)&s3t[k*2];
      const float4 wv = *(const float4*)&W3[k*96 + j4];
      const float se[2] = {sv.x, sv.y};
      const float we[4] = {wv.x, wv.y, wv.z, wv.w};
      #pragma unroll
      for (int m = 0; m < 2; ++m)
        #pragma unroll
        for (int jj = 0; jj < 4; ++jj)
          acc[m][jj] = fmaf(se[m], we[jj], acc[m][jj]);
    }
    #pragma unroll
    for (int m = 0; m < 2; ++m) {
      float4 q = {acc[m][0], acc[m][1], acc[m][2], acc[m][3]};
      *(float4*)&pp[(kq*2 + m)*96 + j4] = q;
    }
  }
  __syncthreads();
  if (tid < 192) {
    const int m = tid / 96, j = tid % 96;
    float v = 17.f * msg_bs[192 + j];
    #pragma unroll
    for (int kq = 0; kq < 16; ++kq) v += pp[(kq*2 + m)*96 + j];
    msgh[j*2 + m] = v;
  }
  __syncthreads();

  // ===== phase 5: LSTM GEMM  gates = [msg|h] @ [Wih;Whh] + gx, 384 thr =====
  {
    const int jg = tid % 48, kq = tid / 48;    // kq 0..7, 24 k each
    const int j8 = jg*8, k0 = kq*24;
    const float* Wb = (kq < 4) ? (W_ih + j8) : (W_hh + j8 - 96*384);
    float acc[2][8];
    #pragma unroll
    for (int m = 0; m < 2; ++m)
      #pragma unroll
      for (int jj = 0; jj < 8; ++jj) acc[m][jj] = 0.f;
    #pragma unroll 2
    for (int k = k0; k < k0 + 24; ++k) {
      const float2 iv = *(const float2*)&msgh[k*2];
      const float* wp = Wb + k*384;
      const float4 wa = *(const float4*)wp;
      const float4 wc = *(const float4*)(wp + 4);
      const float ie[2] = {iv.x, iv.y};
      const float we[8] = {wa.x, wa.y, wa.z, wa.w, wc.x, wc.y, wc.z, wc.w};
      #pragma unroll
      for (int m = 0; m < 2; ++m)
        #pragma unroll
        for (int jj = 0; jj < 8; ++jj)
          acc[m][jj] = fmaf(ie[m], we[jj], acc[m][jj]);
    }
    #pragma unroll
    for (int m = 0; m < 2; ++m) {
      float4 qa = {acc[m][0], acc[m][1], acc[m][2], acc[m][3]};
      float4 qb = {acc[m][4], acc[m][5], acc[m][6], acc[m][7]};
      *(float4*)&pp[(kq*2 + m)*384 + j8]     = qa;
      *(float4*)&pp[(kq*2 + m)*384 + j8 + 4] = qb;
    }
  }
  __syncthreads();
  {
    const int j = tid;
    #pragma unroll
    for (int m = 0; m < 2; ++m) {
      float g = gx[(base+m)*384 + j];
      #pragma unroll
      for (int kq = 0; kq < 8; ++kq) g += pp[(kq*2 + m)*384 + j];
      gates[m*384 + j] = g;
    }
  }
  __syncthreads();

  // ===== phase 6: pointwise LSTM =====
  if (tid < 192) {
    const int m = tid / 96, hj = tid % 96;
    const int node = base + m;
    const float gi = gates[m*384 + hj];
    const float gf = gates[m*384 + 96 + hj];
    const float gg = gates[m*384 + 192 + hj];
    const float go = gates[m*384 + 288 + hj];
    const float sv = s[node*HD + hj];
    const float ig = 1.f/(1.f + expf(-gi));
    const float fg = 1.f/(1.f + expf(-gf));
    const float cg = tanhf(gg);
    const float og = 1.f/(1.f + expf(-go));
    const float s2 = fg*sv + ig*cg;
    const float h2 = og*tanhf(s2);
    s[node*HD + hj] = s2;
    h[node*HD + hj] = h2;
    h2t[hj*2 + m] = h2;
  }
  __syncthreads();

  // ===== phase 7: u_next = h2 @ [W0_edge | W0_self] (+b0 in self half), 384 thr =====
  {
    const int jg = tid % 24, kq = tid / 24;    // kq 0..15, 6 k each
    const int j8 = jg*8, k0 = kq*6;
    const float* Wb = (j8 < 96) ? (msg0_W + j8) : (msg0_W + 9216 + j8 - 96);
    float acc[2][8];
    #pragma unroll
    for (int m = 0; m < 2; ++m)
      #pragma unroll
      for (int jj = 0; jj < 8; ++jj) acc[m][jj] = 0.f;
    #pragma unroll
    for (int kk = 0; kk < 6; ++kk) {
      const int k = k0 + kk;
      const float2 iv = *(const float2*)&h2t[k*2];
      const float* wp = Wb + k*96;
      const float4 wa = *(const float4*)wp;
      const float4 wc = *(const float4*)(wp + 4);
      const float ie[2] = {iv.x, iv.y};
      const float we[8] = {wa.x, wa.y, wa.z, wa.w, wc.x, wc.y, wc.z, wc.w};
      #pragma unroll
      for (int m = 0; m < 2; ++m)
        #pragma unroll
        for (int jj = 0; jj < 8; ++jj)
          acc[m][jj] = fmaf(ie[m], we[jj], acc[m][jj]);
    }
    #pragma unroll
    for (int m = 0; m < 2; ++m) {
      float4 qa = {acc[m][0], acc[m][1], acc[m][2], acc[m][3]};
      float4 qb = {acc[m][4], acc[m][5], acc[m][6], acc[m][7]};
      *(float4*)&pp[(kq*2 + m)*192 + j8]     = qa;
      *(float4*)&pp[(kq*2 + m)*192 + j8 + 4] = qb;
    }
  }
  __syncthreads();
  {
    const int j = tid % 192, m = tid / 192;
    float v = (j >= 96) ? msg0_b[j - 96] : 0.f;   // fold b0 into self half
    #pragma unroll
    for (int kq = 0; kq < 16; ++kq) v += pp[(kq*2 + m)*192 + j];
    u_next[(base+m)*192 + j] = v;
  }

  // ===== phase 8: prediction head (no barrier needed: h2t stable, lgt disjoint) =====
  if (tid < 128) {
    const int m = tid >> 6, c = (tid >> 3) & 7, kq = tid & 7;
    float p = 0.f;
    #pragma unroll
    for (int kk = 0; kk < 12; ++kk) {
      const int k = kq*12 + kk;
      p = fmaf(h2t[k*2 + m], pred_W[k*8 + c], p);
    }
    p += __shfl_xor(p, 1);
    p += __shfl_xor(p, 2);
    p += __shfl_xor(p, 4);
    if (kq == 0) lgt[m*8 + c] = p + pred_b[c];
  }
  __syncthreads();
  if (tid < 2) {
    const int m = tid;
    const int node = base + m;
    float mx = lgt[m*8];
    int pred = 0;
    #pragma unroll
    for (int c = 1; c < 8; ++c) {
      const float v = lgt[m*8 + c];
      if (v > mx) { mx = v; pred = c; }
    }
    float sum = 0.f;
    #pragma unroll
    for (int c = 0; c < 8; ++c) sum += expf(lgt[m*8 + c] - mx);
    const float lse = mx + logf(sum);
    const int tgt = target[node] - 1;
    lgt[16 + m] = lse - lgt[m*8 + tgt];      // -logp
    lgt[18 + m] = (pred == tgt) ? 1.f : 0.f;
    if (step == NSTEPS-1) final_pred_out[node] = (float)pred;
    if (m == 0) {
      // lanes 0..1 of this wave wrote above; in-wave order makes this safe
      lossP[step*NBLK + blk] = lgt[16] + lgt[17];
      cntP[step*NBLK + blk] = (int)(lgt[18] + lgt[19]);
    }
  }
}

// ---------------- finalize: accs + loss ----------------
__global__ void finalize_kernel(const float* __restrict__ lossP,
                                const int* __restrict__ cntP,
                                float* __restrict__ out)
{
  __shared__ float sl[32];
  const int tid = threadIdx.x;   // 256
  const int st = tid >> 3, q = tid & 7;
  float lsum = 0.f;
  for (int i = 0; i < 64; ++i) lsum += lossP[st*NBLK + q*64 + i];
  lsum += __shfl_xor(lsum, 1);
  lsum += __shfl_xor(lsum, 2);
  lsum += __shfl_xor(lsum, 4);
  if (q == 0) sl[st] = lsum;
  float okc = 0.f;
  #pragma unroll
  for (int t = 0; t < 2; ++t) {
    const int bbat = q + 8*t;
    int c = 0;
    for (int i = 0; i < 32; ++i) c += cntP[st*NBLK + bbat*32 + i];
    okc += (c == 64) ? 1.f : 0.f;
  }
  okc += __shfl_xor(okc, 1);
  okc += __shfl_xor(okc, 2);
  okc += __shfl_xor(okc, 4);
  if (q == 0) out[1 + st] = okc / 16.f;
  __syncthreads();
  if (tid == 0) {
    float tot = 0.f;
    for (int i = 0; i < 32; ++i) tot += sl[i];
    out[0] = tot / ((float)NODES * (float)NSTEPS);
  }
}

extern "C" void kernel_launch(void* const* d_in, const int* in_sizes, int n_in,
                              void* d_out, int out_size, void* d_ws, size_t ws_size,
                              hipStream_t stream) {
  const int*   x         = (const int*)  d_in[0];
  const int*   target    = (const int*)  d_in[1];
  const int*   edges     = (const int*)  d_in[2];
  const float* digit_emb = (const float*)d_in[3];
  const float* row_emb   = (const float*)d_in[4];
  const float* col_emb   = (const float*)d_in[5];
  const float* in0_W     = (const float*)d_in[6];
  const float* in0_b     = (const float*)d_in[7];
  const float* in_Ws     = (const float*)d_in[8];
  const float* in_bs     = (const float*)d_in[9];
  const float* msg0_W    = (const float*)d_in[10];
  const float* msg0_b    = (const float*)d_in[11];
  const float* msg_Ws    = (const float*)d_in[12];
  const float* msg_bs    = (const float*)d_in[13];
  const float* W_ih      = (const float*)d_in[14];
  const float* W_hh      = (const float*)d_in[15];
  const float* pred_W    = (const float*)d_in[18];
  const float* pred_b    = (const float*)d_in[19];

  float* ws    = (float*)d_ws;
  float* hbuf  = ws + WS_H;
  float* sbuf  = ws + WS_S;
  float* u0    = ws + WS_U0;
  float* u1    = ws + WS_U1;
  float* xin   = ws + WS_XIN;
  float* gxb   = ws + WS_GX;
  float* W1p   = ws + WS_W1P;
  float* W2p   = ws + WS_W2P;
  float* lossP = ws + WS_LOSSP;
  int*   cntP  = (int*)(ws + WS_CNTP);

  // zero h, s, u0 (u1/lossP/cntP fully written each call)
  hipMemsetAsync(d_ws, 0, (size_t)393216*sizeof(float), stream);

  wpad_kernel<<<96, 128, 0, stream>>>(msg_Ws, W1p, W2p);
  init_kernel<<<NODES, HD, 0, stream>>>(x, digit_emb, row_emb, col_emb,
                                        in0_W, in0_b, in_Ws, in_bs,
                                        msg0_b, xin, u0);
  gx_kernel<<<256, 384, 0, stream>>>(xin, W_ih,
                                     (const float*)d_in[16], (const float*)d_in[17],
                                     gxb);

  float* outp = (float*)d_out;
  for (int st = 0; st < NSTEPS; ++st) {
    const float* up = (st & 1) ? u1 : u0;
    float*       un = (st & 1) ? u0 : u1;
    step_kernel<<<NBLK, 384, 0, stream>>>(
        up, un, hbuf, sbuf, gxb, edges,
        W1p, W2p, msg0_W, msg0_b, msg_Ws, msg_bs,
        W_ih, W_hh, pred_W, pred_b,
        target, lossP, cntP, outp + 1 + NSTEPS, st);
  }

  finalize_kernel<<<1, 256, 0, stream>>>(lossP, cntP, outp);
}

// Round 2
// 1097.053 us; speedup vs baseline: 1.2496x; 1.2496x over previous
//
#include <hip/hip_runtime.h>

#define DEG 17
#define NSTEPS 32
#define HD 96
#define NODES 1024

// ---- workspace float offsets ----
#define WS_U0     0          // 196608
#define WS_BAR    196608     // 256 ints (16 counters spaced 16 apart)
#define WS_U1     196864     // 196608
#define WS_XIN    393472     // 98304
#define WS_GX     491776     // 393216
#define WS_LOSSP  884992     // 8192
#define WS_CNTP   893184     // 8192 ints

// ---- LDS float offsets (single block, 39280 floats = 157120 B) ----
#define Z1    0        // [96][80]  (k-major)
#define Z2    7680     // [96][80]
#define P3    0        // overlay: [16][4][96]   (z1 dead)
#define PL    0        // overlay: [8][4][384]   (z1+z2 dead)
#define PU    0        // overlay: [16][4][192]  (z1+z2 dead)
#define W1L   15360    // [96][96]
#define W2L   24576    // [96][96]
#define GXL   33792    // [4][384]
#define GATES 35328    // [4][384]
#define MSGH  36864    // [192][4]  (msg k=0..95, h k=96..191 — h persists across steps)
#define S3T   37632    // [96][4]
#define H2T   38016    // [96][4]
#define SLC   38400    // [4][96]   cell state (persistent)
#define MSGB  38784    // 288
#define M0B   39072    // 96
#define LGT   39168    // 32
#define NBRI  39200    // 80 ints
#define SMTOT 39280

// ---------------- init1: embedding + input MLP -> xin; u0 self-half = msg0_b
__global__ void init_kernel(
    const int* __restrict__ x,
    const float* __restrict__ digit_emb,
    const float* __restrict__ row_emb,
    const float* __restrict__ col_emb,
    const float* __restrict__ in0_W,
    const float* __restrict__ in0_b,
    const float* __restrict__ in_Ws,
    const float* __restrict__ in_bs,
    const float* __restrict__ msg0_b,
    float* __restrict__ xin,
    float* __restrict__ u0)
{
  const int node = blockIdx.x;
  const int j = threadIdx.x;
  const int n = node & 63;
  const int r = n >> 3, c = n & 7;
  __shared__ float feat[48];
  __shared__ float za[HD];
  __shared__ float zb[HD];
  if (j < 16)      feat[j] = digit_emb[x[node]*16 + j];
  else if (j < 32) feat[j] = row_emb[r*16 + (j-16)];
  else if (j < 48) feat[j] = col_emb[c*16 + (j-32)];
  // fold msg0_b into u self-part for step 0 (steps add it in the u epilogue)
  u0[node*192 + 96 + j] = msg0_b[j];
  __syncthreads();
  float a = in0_b[j];
  for (int k = 0; k < 48; ++k) a = fmaf(feat[k], in0_W[k*HD + j], a);
  za[j] = fmaxf(a, 0.f);
  __syncthreads();
  a = in_bs[j];
  for (int k = 0; k < HD; ++k) a = fmaf(za[k], in_Ws[k*HD + j], a);
  zb[j] = fmaxf(a, 0.f);
  __syncthreads();
  a = in_bs[HD + j];
  for (int k = 0; k < HD; ++k) a = fmaf(zb[k], in_Ws[9216 + k*HD + j], a);
  za[j] = fmaxf(a, 0.f);
  __syncthreads();
  a = in_bs[2*HD + j];
  for (int k = 0; k < HD; ++k) a = fmaf(za[k], in_Ws[2*9216 + k*HD + j], a);
  xin[node*HD + j] = a;
}

// ---------------- init2: gx = xin @ W_ih[96:192] + b_ih + b_hh (one-time)
__global__ __launch_bounds__(384) void gx_kernel(
    const float* __restrict__ xin, const float* __restrict__ W_ih,
    const float* __restrict__ b_ih, const float* __restrict__ b_hh,
    float* __restrict__ gx)
{
  __shared__ float xs[4*HD];
  const int tid = threadIdx.x;
  const int base = blockIdx.x * 4;
  {
    const int m = tid / HD, k = tid - m*HD;
    xs[m*HD + k] = xin[(base+m)*HD + k];
  }
  __syncthreads();
  const int j = tid;  // 0..383
  float a0 = b_ih[j] + b_hh[j], a1 = a0, a2 = a0, a3 = a0;
  for (int k = 0; k < HD; ++k) {
    const float w = W_ih[(96+k)*384 + j];
    a0 = fmaf(xs[k], w, a0);
    a1 = fmaf(xs[HD+k], w, a1);
    a2 = fmaf(xs[2*HD+k], w, a2);
    a3 = fmaf(xs[3*HD+k], w, a3);
  }
  gx[(base+0)*384 + j] = a0;
  gx[(base+1)*384 + j] = a1;
  gx[(base+2)*384 + j] = a2;
  gx[(base+3)*384 + j] = a3;
}

// ---------------- persistent solver: 256 blocks (1/CU), all 32 steps ----------------
__global__ __launch_bounds__(512, 1) void solve_kernel(
    const int* __restrict__ edges,
    const float* __restrict__ msg0_W, const float* __restrict__ msg0_b,
    const float* __restrict__ msg_Ws, const float* __restrict__ msg_bs,
    const float* __restrict__ W_ih, const float* __restrict__ W_hh,
    const float* __restrict__ pred_W, const float* __restrict__ pred_b,
    const int* __restrict__ target,
    const float* __restrict__ gx,
    float* __restrict__ u0, float* __restrict__ u1,
    int* bar,
    float* __restrict__ lossP, int* __restrict__ cntP,
    float* __restrict__ final_pred_out)
{
  __shared__ float sm[SMTOT];

  const int tid = threadIdx.x;
  const int blk = blockIdx.x;
  const int bb = blk & 15;           // batch; blocks {bb, bb+16, ...} share it (same XCD if %8 round-robin)
  const int grp = blk >> 4;          // node-group within batch
  const int nbase = grp * 4;         // node-in-batch of m=0
  const int base = bb*64 + nbase;    // global node of m=0

  // ===== one-time LDS fill =====
  for (int i = tid*4; i < 9216; i += 2048) {
    *(float4*)&sm[W1L + i] = *(const float4*)&msg_Ws[i];
    *(float4*)&sm[W2L + i] = *(const float4*)&msg_Ws[9216 + i];
  }
  #pragma unroll
  for (int t = 0; t < 3; ++t) {
    const int idx = t*512 + tid;     // 0..1535
    sm[GXL + idx] = gx[base*384 + idx];
  }
  if (tid < 288) sm[MSGB + tid] = msg_bs[tid];
  if (tid < 96)  sm[M0B + tid]  = msg0_b[tid];
  if (tid < 80) {
    const int m = tid / 20, r = tid % 20;
    ((int*)&sm[NBRI])[tid] = (r < DEG) ? (bb*64 + edges[(nbase+m)*DEG + r])*192 : -1;
  }
  if (tid < 384) {
    sm[SLC + tid] = 0.f;             // cell state
    sm[MSGH + 384 + tid] = 0.f;      // h slots of msgh (k=96..191)
  }
  __syncthreads();

  const float* uP = u0;
  float*       uN = u1;

  for (int st = 0; st < NSTEPS; ++st) {
    // ===== phase 1: z1 gather (480 thr) + s3t zero (32 thr) =====
    if (tid < 480) {
      const int row = tid % 80;          // m*20 + r
      const int kh  = tid / 80;          // 0..5
      const int m = row / 20;
      const int k0 = kh * 16;
      const int nb = ((const int*)&sm[NBRI])[row];
      if (nb >= 0) {
        const float* ue = uP + nb + k0;
        const float* us = uP + (base+m)*192 + 96 + k0;
        #pragma unroll
        for (int t = 0; t < 4; ++t) {
          const float4 a = *(const float4*)(ue + 4*t);
          const float4 b = *(const float4*)(us + 4*t);
          sm[Z1 + (k0+4*t+0)*80 + row] = fmaxf(a.x + b.x, 0.f);
          sm[Z1 + (k0+4*t+1)*80 + row] = fmaxf(a.y + b.y, 0.f);
          sm[Z1 + (k0+4*t+2)*80 + row] = fmaxf(a.z + b.z, 0.f);
          sm[Z1 + (k0+4*t+3)*80 + row] = fmaxf(a.w + b.w, 0.f);
        }
      } else {
        #pragma unroll
        for (int t = 0; t < 16; ++t) sm[Z1 + (k0+t)*80 + row] = 0.f;
      }
    } else {
      const int i = tid - 480;           // 32 threads zero s3t[384]
      #pragma unroll
      for (int t = 0; t < 12; ++t) sm[S3T + t*32 + i] = 0.f;
    }
    __syncthreads();

    // ===== phase 2: GEMM1 z2 = relu(z1 @ W1 + b1), LDS weights =====
    if (tid < 480) {
      const int jg = tid % 24, dg = tid / 24;   // 4 cols, 4 rows
      const int j4 = jg*4, d4 = dg*4;
      float acc[4][4] = {{0.f}};
      #pragma unroll 4
      for (int k = 0; k < 96; ++k) {
        const float4 z = *(const float4*)&sm[Z1 + k*80 + d4];
        const float4 w = *(const float4*)&sm[W1L + k*96 + j4];
        const float ze[4] = {z.x, z.y, z.z, z.w};
        const float we[4] = {w.x, w.y, w.z, w.w};
        #pragma unroll
        for (int dd = 0; dd < 4; ++dd)
          #pragma unroll
          for (int jj = 0; jj < 4; ++jj)
            acc[dd][jj] = fmaf(ze[dd], we[jj], acc[dd][jj]);
      }
      #pragma unroll
      for (int jj = 0; jj < 4; ++jj) {
        const float b1 = sm[MSGB + j4 + jj];
        float4 q;
        q.x = fmaxf(acc[0][jj] + b1, 0.f);
        q.y = fmaxf(acc[1][jj] + b1, 0.f);
        q.z = fmaxf(acc[2][jj] + b1, 0.f);
        q.w = fmaxf(acc[3][jj] + b1, 0.f);
        *(float4*)&sm[Z2 + (j4+jj)*80 + d4] = q;
      }
    }
    __syncthreads();

    // ===== phase 3: GEMM2 + relu + masked row-sum -> s3t =====
    if (tid < 480) {
      const int jg = tid % 24, dg = tid / 24;
      const int j4 = jg*4, d4 = dg*4;
      float acc[4][4] = {{0.f}};
      #pragma unroll 4
      for (int k = 0; k < 96; ++k) {
        const float4 z = *(const float4*)&sm[Z2 + k*80 + d4];
        const float4 w = *(const float4*)&sm[W2L + k*96 + j4];
        const float ze[4] = {z.x, z.y, z.z, z.w};
        const float we[4] = {w.x, w.y, w.z, w.w};
        #pragma unroll
        for (int dd = 0; dd < 4; ++dd)
          #pragma unroll
          for (int jj = 0; jj < 4; ++jj)
            acc[dd][jj] = fmaf(ze[dd], we[jj], acc[dd][jj]);
      }
      const int nd = d4 / 20;           // rows d4..d4+3 never straddle a node (20%4==0)
      const int r0 = d4 - nd*20;
      #pragma unroll
      for (int jj = 0; jj < 4; ++jj) {
        const float b2 = sm[MSGB + 96 + j4 + jj];
        float p = 0.f;
        #pragma unroll
        for (int dd = 0; dd < 4; ++dd)
          if (r0 + dd < DEG) p += fmaxf(acc[dd][jj] + b2, 0.f);
        atomicAdd(&sm[S3T + (j4+jj)*4 + nd], p);
      }
    }
    __syncthreads();

    // ===== phase 4: GEMM3 msg = s3 @ W3 (stream W3 from L2) =====
    if (tid < 384) {
      const int jg = tid % 24, kq = tid / 24;   // 4 cols, kq 0..15 × 6k
      const int j4 = jg*4, k0 = kq*6;
      const float* W3 = msg_Ws + 2*9216;
      float acc[4][4] = {{0.f}};
      #pragma unroll
      for (int kk = 0; kk < 6; ++kk) {
        const int k = k0 + kk;
        const float4 sv = *(const float4*)&sm[S3T + k*4];
        const float4 wv = *(const float4*)&W3[k*96 + j4];
        const float se[4] = {sv.x, sv.y, sv.z, sv.w};
        const float we[4] = {wv.x, wv.y, wv.z, wv.w};
        #pragma unroll
        for (int m = 0; m < 4; ++m)
          #pragma unroll
          for (int jj = 0; jj < 4; ++jj)
            acc[m][jj] = fmaf(se[m], we[jj], acc[m][jj]);
      }
      #pragma unroll
      for (int m = 0; m < 4; ++m) {
        float4 q = {acc[m][0], acc[m][1], acc[m][2], acc[m][3]};
        *(float4*)&sm[P3 + (kq*4 + m)*96 + j4] = q;
      }
    }
    __syncthreads();
    if (tid < 384) {
      const int m = tid / 96, j = tid % 96;
      float v = 17.f * sm[MSGB + 192 + j];
      #pragma unroll
      for (int kq = 0; kq < 16; ++kq) v += sm[P3 + (kq*4 + m)*96 + j];
      sm[MSGH + j*4 + m] = v;
    }
    __syncthreads();

    // ===== phase 5: LSTM GEMM gates = [msg|h] @ [Wih;Whh] + gx (stream W) =====
    {
      const int jg = tid & 63, kq = tid >> 6;   // 6 cols, kq 0..7 × 24k
      const int j6 = jg*6, k0 = kq*24;
      const float* Wb = (k0 < 96) ? (W_ih + (size_t)k0*384) : (W_hh + (size_t)(k0-96)*384);
      float acc[4][6] = {{0.f}};
      #pragma unroll 4
      for (int kk = 0; kk < 24; ++kk) {
        const float4 iv = *(const float4*)&sm[MSGH + (k0+kk)*4];
        const float* wp = Wb + kk*384 + j6;
        const float2 wa = *(const float2*)wp;
        const float2 wb2 = *(const float2*)(wp + 2);
        const float2 wc = *(const float2*)(wp + 4);
        const float ie[4] = {iv.x, iv.y, iv.z, iv.w};
        const float we[6] = {wa.x, wa.y, wb2.x, wb2.y, wc.x, wc.y};
        #pragma unroll
        for (int m = 0; m < 4; ++m)
          #pragma unroll
          for (int jj = 0; jj < 6; ++jj)
            acc[m][jj] = fmaf(ie[m], we[jj], acc[m][jj]);
      }
      #pragma unroll
      for (int m = 0; m < 4; ++m) {
        float2 qa = {acc[m][0], acc[m][1]};
        float2 qb = {acc[m][2], acc[m][3]};
        float2 qc = {acc[m][4], acc[m][5]};
        *(float2*)&sm[PL + (kq*4 + m)*384 + j6]     = qa;
        *(float2*)&sm[PL + (kq*4 + m)*384 + j6 + 2] = qb;
        *(float2*)&sm[PL + (kq*4 + m)*384 + j6 + 4] = qc;
      }
    }
    __syncthreads();
    {
      #pragma unroll
      for (int t = 0; t < 3; ++t) {
        const int idx = t*512 + tid;            // 0..1535 == m*384+j
        const int m = idx / 384, j = idx - m*384;
        float gv = sm[GXL + idx];
        #pragma unroll
        for (int kq = 0; kq < 8; ++kq) gv += sm[PL + (kq*4 + m)*384 + j];
        sm[GATES + idx] = gv;
      }
    }
    __syncthreads();

    // ===== phase 6: pointwise LSTM (h,s stay in LDS) =====
    if (tid < 384) {
      const int m = tid / 96, hj = tid - m*96;
      const float gi = sm[GATES + m*384 + hj];
      const float gf = sm[GATES + m*384 + 96 + hj];
      const float gg = sm[GATES + m*384 + 192 + hj];
      const float go = sm[GATES + m*384 + 288 + hj];
      const float sv = sm[SLC + tid];
      const float ig = 1.f/(1.f + expf(-gi));
      const float fg = 1.f/(1.f + expf(-gf));
      const float cg = tanhf(gg);
      const float og = 1.f/(1.f + expf(-go));
      const float s2 = fg*sv + ig*cg;
      const float h2 = og*tanhf(s2);
      sm[SLC + tid] = s2;
      sm[H2T + hj*4 + m] = h2;
      sm[MSGH + (96+hj)*4 + m] = h2;   // h for next step's LSTM GEMM
    }
    __syncthreads();

    // ===== phase 7: u_next = h2 @ [W0_edge | W0_self] (stream msg0_W) =====
    {
      const int jg = tid & 31, kq = tid >> 5;   // 6 cols (192), kq 0..15 × 6k
      const int j6 = jg*6, k0 = kq*6;
      const float* Wb = (j6 < 96) ? (msg0_W + j6) : (msg0_W + 9216 + j6 - 96);
      float acc[4][6] = {{0.f}};
      #pragma unroll
      for (int kk = 0; kk < 6; ++kk) {
        const int k = k0 + kk;
        const float4 iv = *(const float4*)&sm[H2T + k*4];
        const float* wp = Wb + k*96;
        const float2 wa = *(const float2*)wp;
        const float2 wb2 = *(const float2*)(wp + 2);
        const float2 wc = *(const float2*)(wp + 4);
        const float ie[4] = {iv.x, iv.y, iv.z, iv.w};
        const float we[6] = {wa.x, wa.y, wb2.x, wb2.y, wc.x, wc.y};
        #pragma unroll
        for (int m = 0; m < 4; ++m)
          #pragma unroll
          for (int jj = 0; jj < 6; ++jj)
            acc[m][jj] = fmaf(ie[m], we[jj], acc[m][jj]);
      }
      #pragma unroll
      for (int m = 0; m < 4; ++m) {
        float2 qa = {acc[m][0], acc[m][1]};
        float2 qb = {acc[m][2], acc[m][3]};
        float2 qc = {acc[m][4], acc[m][5]};
        *(float2*)&sm[PU + (kq*4 + m)*192 + j6]     = qa;
        *(float2*)&sm[PU + (kq*4 + m)*192 + j6 + 2] = qb;
        *(float2*)&sm[PU + (kq*4 + m)*192 + j6 + 4] = qc;
      }
    }
    __syncthreads();
    {
      #pragma unroll
      for (int t = 0; t < 2; ++t) {
        const int idx = t*512 + tid;
        if (idx < 768) {
          const int m = idx / 192, j = idx - m*192;
          float v = (j >= 96) ? sm[M0B + j - 96] : 0.f;   // fold b0 into self half
          #pragma unroll
          for (int kq = 0; kq < 16; ++kq) v += sm[PU + (kq*4 + m)*192 + j];
          uN[(base+m)*192 + j] = v;
        }
      }
      // pred head partials (threads 384..511; h2t stable since phase 6)
      if (tid >= 384) {
        const int t2 = tid - 384;
        const int m = t2 >> 5, c = (t2 >> 2) & 7, kq2 = t2 & 3;
        float p = 0.f;
        #pragma unroll
        for (int kk = 0; kk < 24; ++kk) {
          const int k = kq2*24 + kk;
          p = fmaf(sm[H2T + k*4 + m], pred_W[k*8 + c], p);
        }
        p += __shfl_xor(p, 1);
        p += __shfl_xor(p, 2);
        if (kq2 == 0) sm[LGT + m*8 + c] = p + pred_b[c];
      }
    }
    __syncthreads();

    // ===== phase 8: softmax/loss/pred =====
    if (tid < 4) {
      const int m = tid;
      const int node = base + m;
      float mx = sm[LGT + m*8];
      int pred = 0;
      #pragma unroll
      for (int c = 1; c < 8; ++c) {
        const float v = sm[LGT + m*8 + c];
        if (v > mx) { mx = v; pred = c; }
      }
      float sum = 0.f;
      #pragma unroll
      for (int c = 0; c < 8; ++c) sum += expf(sm[LGT + m*8 + c] - mx);
      const float lse = mx + logf(sum);
      const int tgt = target[node] - 1;
      sm[LGT + 16 + m] = lse - sm[LGT + m*8 + tgt];
      sm[LGT + 20 + m] = (pred == tgt) ? 1.f : 0.f;
      if (st == NSTEPS-1) final_pred_out[node] = (float)pred;
      if (m == 0) {
        // lanes 0..3 of this wave wrote above; in-wave order makes this safe
        lossP[st*256 + blk] = sm[LGT+16] + sm[LGT+17] + sm[LGT+18] + sm[LGT+19];
        cntP[st*256 + blk] = (int)(sm[LGT+20] + sm[LGT+21] + sm[LGT+22] + sm[LGT+23]);
      }
    }

    // ===== per-batch barrier (16 blocks), skip after last step =====
    if (st < NSTEPS-1) {
      __syncthreads();   // all uN stores drained (vmcnt) before release
      if (tid == 0) {
        __hip_atomic_fetch_add(&bar[bb*16], 1, __ATOMIC_RELEASE, __HIP_MEMORY_SCOPE_AGENT);
        const int want = 16*(st+1);
        while (__hip_atomic_load(&bar[bb*16], __ATOMIC_RELAXED, __HIP_MEMORY_SCOPE_AGENT) < want)
          __builtin_amdgcn_s_sleep(2);
        __threadfence();   // acquire: invalidate stale L1/L2 before reading peers' u
      }
      __syncthreads();
      float* tp = (float*)uP; uP = uN; uN = tp;
    }
  }
}

// ---------------- finalize: accs + loss ----------------
__global__ void finalize_kernel(const float* __restrict__ lossP,
                                const int* __restrict__ cntP,
                                float* __restrict__ out)
{
  __shared__ float sl[32];
  const int tid = threadIdx.x;   // 256
  const int st = tid >> 3, q = tid & 7;
  float lsum = 0.f;
  for (int i = 0; i < 32; ++i) lsum += lossP[st*256 + q*32 + i];
  lsum += __shfl_xor(lsum, 1);
  lsum += __shfl_xor(lsum, 2);
  lsum += __shfl_xor(lsum, 4);
  if (q == 0) sl[st] = lsum;
  float okc = 0.f;
  #pragma unroll
  for (int t = 0; t < 2; ++t) {
    const int bbat = q + 8*t;                    // batch id
    int c = 0;
    for (int i = 0; i < 16; ++i) c += cntP[st*256 + i*16 + bbat];  // blocks ≡ bbat (mod 16)
    okc += (c == 64) ? 1.f : 0.f;
  }
  okc += __shfl_xor(okc, 1);
  okc += __shfl_xor(okc, 2);
  okc += __shfl_xor(okc, 4);
  if (q == 0) out[1 + st] = okc / 16.f;
  __syncthreads();
  if (tid == 0) {
    float tot = 0.f;
    for (int i = 0; i < 32; ++i) tot += sl[i];
    out[0] = tot / ((float)NODES * (float)NSTEPS);
  }
}

extern "C" void kernel_launch(void* const* d_in, const int* in_sizes, int n_in,
                              void* d_out, int out_size, void* d_ws, size_t ws_size,
                              hipStream_t stream) {
  const int*   x         = (const int*)  d_in[0];
  const int*   target    = (const int*)  d_in[1];
  const int*   edges     = (const int*)  d_in[2];
  const float* digit_emb = (const float*)d_in[3];
  const float* row_emb   = (const float*)d_in[4];
  const float* col_emb   = (const float*)d_in[5];
  const float* in0_W     = (const float*)d_in[6];
  const float* in0_b     = (const float*)d_in[7];
  const float* in_Ws     = (const float*)d_in[8];
  const float* in_bs     = (const float*)d_in[9];
  const float* msg0_W    = (const float*)d_in[10];
  const float* msg0_b    = (const float*)d_in[11];
  const float* msg_Ws    = (const float*)d_in[12];
  const float* msg_bs    = (const float*)d_in[13];
  const float* W_ih      = (const float*)d_in[14];
  const float* W_hh      = (const float*)d_in[15];
  const float* b_ih      = (const float*)d_in[16];
  const float* b_hh      = (const float*)d_in[17];
  const float* pred_W    = (const float*)d_in[18];
  const float* pred_b    = (const float*)d_in[19];

  float* ws    = (float*)d_ws;
  float* u0    = ws + WS_U0;
  int*   bar   = (int*)(ws + WS_BAR);
  float* u1    = ws + WS_U1;
  float* xin   = ws + WS_XIN;
  float* gxb   = ws + WS_GX;
  float* lossP = ws + WS_LOSSP;
  int*   cntP  = (int*)(ws + WS_CNTP);

  // zero u0 (edge halves) + barrier counters; everything else fully written
  hipMemsetAsync(d_ws, 0, (size_t)(196608 + 256)*sizeof(float), stream);

  init_kernel<<<NODES, HD, 0, stream>>>(x, digit_emb, row_emb, col_emb,
                                        in0_W, in0_b, in_Ws, in_bs,
                                        msg0_b, xin, u0);
  gx_kernel<<<256, 384, 0, stream>>>(xin, W_ih, b_ih, b_hh, gxb);

  float* outp = (float*)d_out;
  solve_kernel<<<256, 512, 0, stream>>>(
      edges, msg0_W, msg0_b, msg_Ws, msg_bs,
      W_ih, W_hh, pred_W, pred_b, target, gxb,
      u0, u1, bar, lossP, cntP, outp + 1 + NSTEPS);

  finalize_kernel<<<1, 256, 0, stream>>>(lossP, cntP, outp);
}

// Round 3
// 1033.514 us; speedup vs baseline: 1.3264x; 1.0615x over previous
//
#include <hip/hip_runtime.h>

#define DEG 17
#define NSTEPS 32
#define HD 96

// ---- workspace float offsets ----
#define WS_U0     0          // 196608
#define WS_BAR    196608     // 256 ints (16 counters spaced 16 apart)
#define WS_U1     196864     // 196608
#define WS_XIN    393472     // 98304
#define WS_GX     491776     // 393216
#define WS_LOSSP  884992     // 16384 floats (32 steps * 512)
#define WS_CNTP   901376     // 16384 ints

// ---- LDS layout (floats) ----
// shared (read-only after init):
#define W1L   0        // 9216  [96][96]
#define W2L   9216     // 9216  [96][96]
#define MSGB  18432    // 288
#define M0B   18720    // 96
#define VBASE 18816
#define VSTR  10272
// per-vblock relative offsets (2 nodes per vblock):
#define VZ1    0       // 3840 [96][40] k-major; overlays: P3[16][96]=1536, PL[8][384]=3072, PU[16][192]=3072
#define VZ2    3840    // 3840 [96][40]
#define VGX    7680    // 768  [2][384]
#define VGATES 8448    // 768  [2][384]
#define VMSGH  9216    // 384  [192][2] (msg k=0..95, h k=96..191; h persists)
#define VS3T   9600    // 192  [96][2]
#define VH2T   9792    // 192  [96][2]
#define VSLC   9984    // 192  [2][96] cell state (persistent)
#define VLGT   10176   // 32
#define VNBRI  10208   // 40 ints
#define BARC  (VBASE + 2*VSTR)   // 2 ints (vblock barrier counters)
#define SMTOT (BARC + 8)         // 39368 floats = 157472 B

// ---------------- init1: embedding + input MLP -> xin; u0 self-half = msg0_b
__global__ void init_kernel(
    const int* __restrict__ x,
    const float* __restrict__ digit_emb,
    const float* __restrict__ row_emb,
    const float* __restrict__ col_emb,
    const float* __restrict__ in0_W,
    const float* __restrict__ in0_b,
    const float* __restrict__ in_Ws,
    const float* __restrict__ in_bs,
    const float* __restrict__ msg0_b,
    float* __restrict__ xin,
    float* __restrict__ u0)
{
  const int node = blockIdx.x;
  const int j = threadIdx.x;
  const int n = node & 63;
  const int r = n >> 3, c = n & 7;
  __shared__ float feat[48];
  __shared__ float za[HD];
  __shared__ float zb[HD];
  if (j < 16)      feat[j] = digit_emb[x[node]*16 + j];
  else if (j < 32) feat[j] = row_emb[r*16 + (j-16)];
  else if (j < 48) feat[j] = col_emb[c*16 + (j-32)];
  u0[node*192 + 96 + j] = msg0_b[j];
  __syncthreads();
  float a = in0_b[j];
  for (int k = 0; k < 48; ++k) a = fmaf(feat[k], in0_W[k*HD + j], a);
  za[j] = fmaxf(a, 0.f);
  __syncthreads();
  a = in_bs[j];
  for (int k = 0; k < HD; ++k) a = fmaf(za[k], in_Ws[k*HD + j], a);
  zb[j] = fmaxf(a, 0.f);
  __syncthreads();
  a = in_bs[HD + j];
  for (int k = 0; k < HD; ++k) a = fmaf(zb[k], in_Ws[9216 + k*HD + j], a);
  za[j] = fmaxf(a, 0.f);
  __syncthreads();
  a = in_bs[2*HD + j];
  for (int k = 0; k < HD; ++k) a = fmaf(za[k], in_Ws[2*9216 + k*HD + j], a);
  xin[node*HD + j] = a;
}

// ---------------- init2: gx = xin @ W_ih[96:192] + b_ih + b_hh (one-time)
__global__ __launch_bounds__(384) void gx_kernel(
    const float* __restrict__ xin, const float* __restrict__ W_ih,
    const float* __restrict__ b_ih, const float* __restrict__ b_hh,
    float* __restrict__ gx)
{
  __shared__ float xs[4*HD];
  const int tid = threadIdx.x;
  const int base = blockIdx.x * 4;
  {
    const int m = tid / HD, k = tid - m*HD;
    xs[m*HD + k] = xin[(base+m)*HD + k];
  }
  __syncthreads();
  const int j = tid;  // 0..383
  float a0 = b_ih[j] + b_hh[j], a1 = a0, a2 = a0, a3 = a0;
  for (int k = 0; k < HD; ++k) {
    const float w = W_ih[(96+k)*384 + j];
    a0 = fmaf(xs[k], w, a0);
    a1 = fmaf(xs[HD+k], w, a1);
    a2 = fmaf(xs[2*HD+k], w, a2);
    a3 = fmaf(xs[3*HD+k], w, a3);
  }
  gx[(base+0)*384 + j] = a0;
  gx[(base+1)*384 + j] = a1;
  gx[(base+2)*384 + j] = a2;
  gx[(base+3)*384 + j] = a3;
}

// per-vblock barrier over 4 waves: LDS counter, monotonically increasing target
__device__ __forceinline__ void vbar(int* c, int want) {
  if ((threadIdx.x & 63) == 0)
    __hip_atomic_fetch_add(c, 1, __ATOMIC_RELEASE, __HIP_MEMORY_SCOPE_WORKGROUP);
  while (__hip_atomic_load(c, __ATOMIC_ACQUIRE, __HIP_MEMORY_SCOPE_WORKGROUP) < want)
    __builtin_amdgcn_s_sleep(1);
}

// ---------------- persistent solver: 256 blocks (1/CU), 2 vblocks of 4 waves ----------------
__global__ __launch_bounds__(512, 1) void solve_kernel(
    const int* __restrict__ edges,
    const float* __restrict__ msg0_W, const float* __restrict__ msg0_b,
    const float* __restrict__ msg_Ws, const float* __restrict__ msg_bs,
    const float* __restrict__ W_ih, const float* __restrict__ W_hh,
    const float* __restrict__ pred_W, const float* __restrict__ pred_b,
    const int* __restrict__ target,
    const float* __restrict__ gx,
    float* __restrict__ u0, float* __restrict__ u1,
    int* bar,
    float* __restrict__ lossP, int* __restrict__ cntP,
    float* __restrict__ final_pred_out)
{
  __shared__ float sm[SMTOT];

  const int tid = threadIdx.x;
  const int vb  = tid >> 8;          // vblock 0/1 (waves 0-3 / 4-7 -> 1 wave each per SIMD)
  const int vt  = tid & 255;         // thread-in-vblock
  const int blk = blockIdx.x;
  const int bb  = blk & 15;          // batch; blocks == bb (mod 16) -> same XCD under %8 round-robin
  const int grp = blk >> 4;
  const int base = bb*64 + grp*4;    // first node of block
  const int gbase = base + vb*2;     // first node of vblock

  float* const vs = sm + VBASE + vb*VSTR;
  int* const vnbri = (int*)(vs + VNBRI);
  int* const vbc = (int*)(sm + BARC) + vb;

  // ===== one-time LDS fill =====
  for (int i = tid*4; i < 9216; i += 2048) {
    *(float4*)&sm[W1L + i] = *(const float4*)&msg_Ws[i];
    *(float4*)&sm[W2L + i] = *(const float4*)&msg_Ws[9216 + i];
  }
  if (tid < 288) sm[MSGB + tid] = msg_bs[tid];
  if (tid < 96)  sm[M0B + tid]  = msg0_b[tid];
  if (tid < 2)   ((int*)(sm + BARC))[tid] = 0;
  #pragma unroll
  for (int t = 0; t < 3; ++t) {
    const int idx = t*256 + vt;      // 0..767
    vs[VGX + idx] = gx[gbase*384 + idx];
  }
  if (vt < 192) {
    vs[VSLC + vt] = 0.f;             // cell state
    vs[VMSGH + 192 + vt] = 0.f;      // h slots (k=96..191)
  }
  if (vt < 40) {
    const int m = vt / 20, r = vt % 20;
    vnbri[vt] = (r < DEG) ? (bb*64 + edges[((grp*4 + vb*2) + m)*DEG + r])*192 : -1;
  }
  __syncthreads();

  const float* uP = u0;
  float*       uN = u1;
  int vph = 0;

  for (int st = 0; st < NSTEPS; ++st) {
    // ===== phase 1: z1 gather (240 thr) + s3t zero (16 thr) =====
    if (vt < 240) {
      const int row = vt % 40;       // m*20 + r
      const int kh  = vt / 40;       // 0..5
      const int m = row / 20;
      const int k0 = kh * 16;
      const int nb = vnbri[row];
      if (nb >= 0) {
        const float* ue = uP + nb + k0;
        const float* us = uP + (gbase+m)*192 + 96 + k0;
        #pragma unroll
        for (int t = 0; t < 4; ++t) {
          const float4 a = *(const float4*)(ue + 4*t);
          const float4 b = *(const float4*)(us + 4*t);
          vs[VZ1 + (k0+4*t+0)*40 + row] = fmaxf(a.x + b.x, 0.f);
          vs[VZ1 + (k0+4*t+1)*40 + row] = fmaxf(a.y + b.y, 0.f);
          vs[VZ1 + (k0+4*t+2)*40 + row] = fmaxf(a.z + b.z, 0.f);
          vs[VZ1 + (k0+4*t+3)*40 + row] = fmaxf(a.w + b.w, 0.f);
        }
      } else {
        #pragma unroll
        for (int t = 0; t < 16; ++t) vs[VZ1 + (k0+t)*40 + row] = 0.f;
      }
    } else {
      const int i = vt - 240;        // 16 threads zero VS3T[192]
      #pragma unroll
      for (int t = 0; t < 12; ++t) vs[VS3T + i*12 + t] = 0.f;
    }
    vph += 4; vbar(vbc, vph);

    // ===== phase 2: GEMM1 z2 = relu(z1 @ W1 + b1), LDS W =====
    if (vt < 240) {
      const int jg = vt % 24, dg = vt / 24;   // 4 cols, 4 rows
      const int j4 = jg*4, d4 = dg*4;
      float acc[4][4] = {{0.f}};
      #pragma unroll 4
      for (int k = 0; k < 96; ++k) {
        const float4 z = *(const float4*)&vs[VZ1 + k*40 + d4];
        const float4 w = *(const float4*)&sm[W1L + k*96 + j4];
        const float ze[4] = {z.x, z.y, z.z, z.w};
        const float we[4] = {w.x, w.y, w.z, w.w};
        #pragma unroll
        for (int dd = 0; dd < 4; ++dd)
          #pragma unroll
          for (int jj = 0; jj < 4; ++jj)
            acc[dd][jj] = fmaf(ze[dd], we[jj], acc[dd][jj]);
      }
      #pragma unroll
      for (int jj = 0; jj < 4; ++jj) {
        const float b1 = sm[MSGB + j4 + jj];
        float4 q;
        q.x = fmaxf(acc[0][jj] + b1, 0.f);
        q.y = fmaxf(acc[1][jj] + b1, 0.f);
        q.z = fmaxf(acc[2][jj] + b1, 0.f);
        q.w = fmaxf(acc[3][jj] + b1, 0.f);
        *(float4*)&vs[VZ2 + (j4+jj)*40 + d4] = q;
      }
    }
    vph += 4; vbar(vbc, vph);

    // ===== phase 3: GEMM2 + relu + masked row-sum -> s3t =====
    if (vt < 240) {
      const int jg = vt % 24, dg = vt / 24;
      const int j4 = jg*4, d4 = dg*4;
      float acc[4][4] = {{0.f}};
      #pragma unroll 4
      for (int k = 0; k < 96; ++k) {
        const float4 z = *(const float4*)&vs[VZ2 + k*40 + d4];
        const float4 w = *(const float4*)&sm[W2L + k*96 + j4];
        const float ze[4] = {z.x, z.y, z.z, z.w};
        const float we[4] = {w.x, w.y, w.z, w.w};
        #pragma unroll
        for (int dd = 0; dd < 4; ++dd)
          #pragma unroll
          for (int jj = 0; jj < 4; ++jj)
            acc[dd][jj] = fmaf(ze[dd], we[jj], acc[dd][jj]);
      }
      const int nd = d4 / 20;        // d4 in {0..36}; rows never straddle a node
      const int r0 = d4 - nd*20;
      #pragma unroll
      for (int jj = 0; jj < 4; ++jj) {
        const float b2 = sm[MSGB + 96 + j4 + jj];
        float p = 0.f;
        #pragma unroll
        for (int dd = 0; dd < 4; ++dd)
          if (r0 + dd < DEG) p += fmaxf(acc[dd][jj] + b2, 0.f);
        atomicAdd(&vs[VS3T + (j4+jj)*2 + nd], p);
      }
    }
    vph += 4; vbar(vbc, vph);

    // ===== phase 4: GEMM3 msg = s3 @ W3 (stream W3 from L2) =====
    if (vt < 192) {
      const int jg = vt % 24, kq = vt / 24;   // kq 0..7, 12 k each
      const int j4 = jg*4, k0 = kq*12;
      const float* W3 = msg_Ws + 2*9216;
      float acc[2][4] = {{0.f}};
      #pragma unroll
      for (int kk = 0; kk < 12; ++kk) {
        const int k = k0 + kk;
        const float2 sv = *(const float2*)&vs[VS3T + k*2];
        const float4 wv = *(const float4*)&W3[k*96 + j4];
        const float se[2] = {sv.x, sv.y};
        const float we[4] = {wv.x, wv.y, wv.z, wv.w};
        #pragma unroll
        for (int m = 0; m < 2; ++m)
          #pragma unroll
          for (int jj = 0; jj < 4; ++jj)
            acc[m][jj] = fmaf(se[m], we[jj], acc[m][jj]);
      }
      #pragma unroll
      for (int m = 0; m < 2; ++m) {
        float4 q = {acc[m][0], acc[m][1], acc[m][2], acc[m][3]};
        *(float4*)&vs[VZ1 + (kq*2 + m)*96 + j4] = q;    // P3 overlay
      }
    }
    vph += 4; vbar(vbc, vph);
    if (vt < 192) {
      const int m = vt / 96, j = vt % 96;
      float v = 17.f * sm[MSGB + 192 + j];
      #pragma unroll
      for (int kq = 0; kq < 8; ++kq) v += vs[VZ1 + (kq*2 + m)*96 + j];
      vs[VMSGH + j*2 + m] = v;
    }
    vph += 4; vbar(vbc, vph);

    // ===== phase 5: LSTM GEMM gates = [msg|h] @ [Wih;Whh] + gx (stream W) =====
    {
      const int jg = vt & 63, kq = vt >> 6;   // 6 cols, kq 0..3 x 48k
      const int j6 = jg*6, k0 = kq*48;
      const float* Wb = (k0 < 96) ? (W_ih + (size_t)k0*384) : (W_hh + (size_t)(k0-96)*384);
      float acc[2][6] = {{0.f}};
      #pragma unroll 4
      for (int kk = 0; kk < 48; ++kk) {
        const float2 iv = *(const float2*)&vs[VMSGH + (k0+kk)*2];
        const float* wp = Wb + kk*384 + j6;
        const float2 wa = *(const float2*)wp;
        const float2 wb2 = *(const float2*)(wp + 2);
        const float2 wc = *(const float2*)(wp + 4);
        const float ie[2] = {iv.x, iv.y};
        const float we[6] = {wa.x, wa.y, wb2.x, wb2.y, wc.x, wc.y};
        #pragma unroll
        for (int m = 0; m < 2; ++m)
          #pragma unroll
          for (int jj = 0; jj < 6; ++jj)
            acc[m][jj] = fmaf(ie[m], we[jj], acc[m][jj]);
      }
      #pragma unroll
      for (int m = 0; m < 2; ++m) {
        float2 qa = {acc[m][0], acc[m][1]};
        float2 qb = {acc[m][2], acc[m][3]};
        float2 qc = {acc[m][4], acc[m][5]};
        *(float2*)&vs[VZ1 + (kq*2 + m)*384 + j6]     = qa;   // PL overlay
        *(float2*)&vs[VZ1 + (kq*2 + m)*384 + j6 + 2] = qb;
        *(float2*)&vs[VZ1 + (kq*2 + m)*384 + j6 + 4] = qc;
      }
    }
    vph += 4; vbar(vbc, vph);
    {
      #pragma unroll
      for (int t = 0; t < 3; ++t) {
        const int idx = t*256 + vt;            // 0..767 == m*384+j
        const int m = idx / 384, j = idx - m*384;
        float gv = vs[VGX + idx];
        #pragma unroll
        for (int kq = 0; kq < 4; ++kq) gv += vs[VZ1 + (kq*2 + m)*384 + j];
        vs[VGATES + idx] = gv;
      }
    }
    vph += 4; vbar(vbc, vph);

    // ===== phase 6: pointwise LSTM (h,s stay in LDS) =====
    if (vt < 192) {
      const int m = vt / 96, hj = vt - m*96;
      const float gi = vs[VGATES + m*384 + hj];
      const float gf = vs[VGATES + m*384 + 96 + hj];
      const float gg = vs[VGATES + m*384 + 192 + hj];
      const float go = vs[VGATES + m*384 + 288 + hj];
      const float sv = vs[VSLC + vt];
      const float ig = 1.f/(1.f + expf(-gi));
      const float fg = 1.f/(1.f + expf(-gf));
      const float cg = tanhf(gg);
      const float og = 1.f/(1.f + expf(-go));
      const float s2 = fg*sv + ig*cg;
      const float h2 = og*tanhf(s2);
      vs[VSLC + vt] = s2;
      vs[VH2T + hj*2 + m] = h2;
      vs[VMSGH + (96+hj)*2 + m] = h2;   // h for next step's LSTM GEMM
    }
    vph += 4; vbar(vbc, vph);

    // ===== phase 7: u_next = h2 @ [W0_edge | W0_self] (stream msg0_W) =====
    {
      const int jg = vt & 31, kq = vt >> 5;   // 6 cols (192), kq 0..7 x 12k
      const int j6 = jg*6, k0 = kq*12;
      const float* Wb = (j6 < 96) ? (msg0_W + j6) : (msg0_W + 9216 + j6 - 96);
      float acc[2][6] = {{0.f}};
      #pragma unroll
      for (int kk = 0; kk < 12; ++kk) {
        const int k = k0 + kk;
        const float2 iv = *(const float2*)&vs[VH2T + k*2];
        const float* wp = Wb + k*96;
        const float2 wa = *(const float2*)wp;
        const float2 wb2 = *(const float2*)(wp + 2);
        const float2 wc = *(const float2*)(wp + 4);
        const float ie[2] = {iv.x, iv.y};
        const float we[6] = {wa.x, wa.y, wb2.x, wb2.y, wc.x, wc.y};
        #pragma unroll
        for (int m = 0; m < 2; ++m)
          #pragma unroll
          for (int jj = 0; jj < 6; ++jj)
            acc[m][jj] = fmaf(ie[m], we[jj], acc[m][jj]);
      }
      #pragma unroll
      for (int m = 0; m < 2; ++m) {
        float2 qa = {acc[m][0], acc[m][1]};
        float2 qb = {acc[m][2], acc[m][3]};
        float2 qc = {acc[m][4], acc[m][5]};
        *(float2*)&vs[VZ1 + (kq*2 + m)*192 + j6]     = qa;   // PU overlay
        *(float2*)&vs[VZ1 + (kq*2 + m)*192 + j6 + 2] = qb;
        *(float2*)&vs[VZ1 + (kq*2 + m)*192 + j6 + 4] = qc;
      }
    }
    vph += 4; vbar(vbc, vph);
    if (vt < 192) {
      #pragma unroll
      for (int t = 0; t < 2; ++t) {
        const int idx = t*192 + vt;            // 0..383
        const int m = idx / 192, j = idx - m*192;
        float v = (j >= 96) ? sm[M0B + j - 96] : 0.f;   // fold b0 into self half
        #pragma unroll
        for (int kq = 0; kq < 8; ++kq) v += vs[VZ1 + (kq*2 + m)*192 + j];
        uN[(gbase+m)*192 + j] = v;
      }
    } else {
      // pred head partials (wave 3 of vblock; h2t stable since phase 6)
      const int t2 = vt - 192;
      const int m = t2 >> 5, c = (t2 >> 2) & 7, kq2 = t2 & 3;
      float p = 0.f;
      #pragma unroll
      for (int kk = 0; kk < 24; ++kk) {
        const int k = kq2*24 + kk;
        p = fmaf(vs[VH2T + k*2 + m], pred_W[k*8 + c], p);
      }
      p += __shfl_xor(p, 1);
      p += __shfl_xor(p, 2);
      if (kq2 == 0) vs[VLGT + m*8 + c] = p + pred_b[c];
    }
    vph += 4; vbar(vbc, vph);

    // ===== phase 8: softmax/loss/pred =====
    if (vt < 2) {
      const int m = vt;
      const int node = gbase + m;
      float mx = vs[VLGT + m*8];
      int pred = 0;
      #pragma unroll
      for (int c = 1; c < 8; ++c) {
        const float v = vs[VLGT + m*8 + c];
        if (v > mx) { mx = v; pred = c; }
      }
      float sum = 0.f;
      #pragma unroll
      for (int c = 0; c < 8; ++c) sum += expf(vs[VLGT + m*8 + c] - mx);
      const float lse = mx + logf(sum);
      const int tgt = target[node] - 1;
      vs[VLGT + 16 + m] = lse - vs[VLGT + m*8 + tgt];
      vs[VLGT + 20 + m] = (pred == tgt) ? 1.f : 0.f;
      if (st == NSTEPS-1) final_pred_out[node] = (float)pred;
      if (m == 0) {
        // lanes 0,1 of this wave wrote above; in-wave instruction order makes this safe
        lossP[st*512 + bb*32 + grp*2 + vb] = vs[VLGT+16] + vs[VLGT+17];
        cntP[st*512 + bb*32 + grp*2 + vb] = (int)(vs[VLGT+20] + vs[VLGT+21]);
      }
    }

    // ===== per-batch barrier (16 blocks), skip after last step =====
    if (st < NSTEPS-1) {
      __syncthreads();   // joins both vblocks; drains vmcnt for all uN stores
      if (tid == 0) {
        __hip_atomic_fetch_add(&bar[bb*16], 1, __ATOMIC_RELEASE, __HIP_MEMORY_SCOPE_AGENT);
        const int want = 16*(st+1);
        while (__hip_atomic_load(&bar[bb*16], __ATOMIC_RELAXED, __HIP_MEMORY_SCOPE_AGENT) < want)
          __builtin_amdgcn_s_sleep(2);
        __threadfence();   // acquire before reading peers' u
      }
      __syncthreads();
      float* tp = (float*)uP; uP = uN; uN = tp;
    }
  }
}

// ---------------- finalize: accs + loss ----------------
__global__ void finalize_kernel(const float* __restrict__ lossP,
                                const int* __restrict__ cntP,
                                float* __restrict__ out)
{
  __shared__ float sl[32];
  const int tid = threadIdx.x;   // 256
  const int st = tid >> 3, q = tid & 7;
  float lsum = 0.f;
  for (int i = 0; i < 64; ++i) lsum += lossP[st*512 + q*64 + i];
  lsum += __shfl_xor(lsum, 1);
  lsum += __shfl_xor(lsum, 2);
  lsum += __shfl_xor(lsum, 4);
  if (q == 0) sl[st] = lsum;
  float okc = 0.f;
  #pragma unroll
  for (int t = 0; t < 2; ++t) {
    const int bbat = q + 8*t;                    // batch id
    int c = 0;
    for (int i = 0; i < 32; ++i) c += cntP[st*512 + bbat*32 + i];
    okc += (c == 64) ? 1.f : 0.f;
  }
  okc += __shfl_xor(okc, 1);
  okc += __shfl_xor(okc, 2);
  okc += __shfl_xor(okc, 4);
  if (q == 0) out[1 + st] = okc / 16.f;
  __syncthreads();
  if (tid == 0) {
    float tot = 0.f;
    for (int i = 0; i < 32; ++i) tot += sl[i];
    out[0] = tot / (1024.f * (float)NSTEPS);
  }
}

extern "C" void kernel_launch(void* const* d_in, const int* in_sizes, int n_in,
                              void* d_out, int out_size, void* d_ws, size_t ws_size,
                              hipStream_t stream) {
  const int*   x         = (const int*)  d_in[0];
  const int*   target    = (const int*)  d_in[1];
  const int*   edges     = (const int*)  d_in[2];
  const float* digit_emb = (const float*)d_in[3];
  const float* row_emb   = (const float*)d_in[4];
  const float* col_emb   = (const float*)d_in[5];
  const float* in0_W     = (const float*)d_in[6];
  const float* in0_b     = (const float*)d_in[7];
  const float* in_Ws     = (const float*)d_in[8];
  const float* in_bs     = (const float*)d_in[9];
  const float* msg0_W    = (const float*)d_in[10];
  const float* msg0_b    = (const float*)d_in[11];
  const float* msg_Ws    = (const float*)d_in[12];
  const float* msg_bs    = (const float*)d_in[13];
  const float* W_ih      = (const float*)d_in[14];
  const float* W_hh      = (const float*)d_in[15];
  const float* b_ih      = (const float*)d_in[16];
  const float* b_hh      = (const float*)d_in[17];
  const float* pred_W    = (const float*)d_in[18];
  const float* pred_b    = (const float*)d_in[19];

  float* ws    = (float*)d_ws;
  float* u0    = ws + WS_U0;
  int*   bar   = (int*)(ws + WS_BAR);
  float* u1    = ws + WS_U1;
  float* xin   = ws + WS_XIN;
  float* gxb   = ws + WS_GX;
  float* lossP = ws + WS_LOSSP;
  int*   cntP  = (int*)(ws + WS_CNTP);

  // zero u0 (edge halves) + barrier counters; everything else fully written
  hipMemsetAsync(d_ws, 0, (size_t)(196608 + 256)*sizeof(float), stream);

  init_kernel<<<1024, HD, 0, stream>>>(x, digit_emb, row_emb, col_emb,
                                       in0_W, in0_b, in_Ws, in_bs,
                                       msg0_b, xin, u0);
  gx_kernel<<<256, 384, 0, stream>>>(xin, W_ih, b_ih, b_hh, gxb);

  float* outp = (float*)d_out;
  solve_kernel<<<256, 512, 0, stream>>>(
      edges, msg0_W, msg0_b, msg_Ws, msg_bs,
      W_ih, W_hh, pred_W, pred_b, target, gxb,
      u0, u1, bar, lossP, cntP, outp + 1 + NSTEPS);

  finalize_kernel<<<1, 256, 0, stream>>>(lossP, cntP, outp);
}